// Round 3
// baseline (45.742 us; speedup 1.0000x reference)
//
#include <hip/hip_runtime.h>
#include <hip/hip_bf16.h>
#include <math.h>

#define B_IMG 16
#define H_DIM 640
#define W_DIM 640
#define W4    160                       // float4 per row
#define RPB   8                         // rows per block
#define BLK_F4 (RPB * W4)               // 1280 float4 per block
#define BPI   (H_DIM / RPB)             // 80 blocks per image
#define GRID  (B_IMG * BPI)             // 1280 blocks, each owns 8 rows of ONE image
#define NT    256
#define KITER (BLK_F4 / NT)             // 5 float4 per thread
#define NWORDS (W_DIM / 32)             // 20 u32 per row bitmask
#define NPIX  ((float)B_IMG * H_DIM * W_DIM)
#define LOSS_WEIGHT 0.1f
#define LN2F 0.69314718055994530942f
#define MAXB 512

__device__ __forceinline__ float softplus_fast(float v) {
    return fmaxf(v, 0.0f) + __logf(1.0f + __expf(-fabsf(v)));
}

__global__ void __launch_bounds__(NT)
fused(const float4* __restrict__ seg4,
      const float*  __restrict__ bboxes,
      const int*    __restrict__ batch_idx,
      const unsigned char* __restrict__ is_seg,
      int M,
      float2*   __restrict__ partial,   // [GRID]
      unsigned* __restrict__ counter,   // zeroed each call via memset node
      float*    __restrict__ out)
{
    __shared__ int      s_n;
    __shared__ int4     s_box[MAXB];                // this image's boxes (x1,y1,x2,y2)
    __shared__ unsigned s_mask[RPB * NWORDS];       // 8 rows x 640-bit
    __shared__ float    s_r1[NT / 64], s_r2[NT / 64];
    __shared__ int      s_last;
    __shared__ int      s_has[B_IMG];

    const int tid = threadIdx.x;
    const int bid = blockIdx.x;
    const int b   = bid / BPI;                      // image (uniform per block)
    const int y0  = (bid - b * BPI) * RPB;          // first row in image

    if (tid == 0) s_n = 0;
    __syncthreads();

    // --- gather this image's boxes (f32 math, clip [0,dim-1], trunc = ref) ---
    for (int m = tid; m < M; m += NT) {
        int bi = batch_idx[m];
        bi = min(max(bi, 0), B_IMG - 1);
        if (bi == b) {
            float cx = bboxes[4*m+0] * (float)W_DIM;
            float cy = bboxes[4*m+1] * (float)H_DIM;
            float bw = bboxes[4*m+2] * (float)W_DIM;
            float bh = bboxes[4*m+3] * (float)H_DIM;
            int x1 = (int)fminf(fmaxf(cx - bw*0.5f, 0.0f), (float)(W_DIM-1));
            int y1 = (int)fminf(fmaxf(cy - bh*0.5f, 0.0f), (float)(H_DIM-1));
            int x2 = (int)fminf(fmaxf(cx + bw*0.5f, 0.0f), (float)(W_DIM-1));
            int y2 = (int)fminf(fmaxf(cy + bh*0.5f, 0.0f), (float)(H_DIM-1));
            int p = atomicAdd(&s_n, 1);
            if (p < MAXB) s_box[p] = make_int4(x1, y1, x2, y2);
        }
    }
    __syncthreads();
    const int nb  = min(s_n, MAXB);
    const int eff = (is_seg[b] == 0 && nb > 0) ? 1 : 0;

    float sp_sum = 0.0f, mx_sum = 0.0f;

    if (eff) {
        // --- build per-row bitmasks: pair p = (row_local, word) ---
        if (tid < RPB * NWORDS) {
            int row  = tid / NWORDS;
            int word = tid - row * NWORDS;
            int y    = y0 + row;
            int wx0  = word * 32;
            unsigned acc = 0u;
            for (int i = 0; i < nb; ++i) {
                int4 bx = s_box[i];
                if (y >= bx.y && y <= bx.w) {
                    int lo = max(bx.x, wx0);
                    int hi = min(bx.z, wx0 + 31);
                    if (lo <= hi) {
                        unsigned span = (unsigned)(hi - lo + 1);
                        unsigned mset = (span >= 32u) ? 0xFFFFFFFFu
                                                      : ((1u << span) - 1u);
                        acc |= mset << (lo - wx0);
                    }
                }
            }
            s_mask[tid] = acc;
        }
        __syncthreads();

        // --- stream 5 float4 per thread, contiguous chunk, mask via bit test ---
        const size_t base = (size_t)bid * BLK_F4;
#pragma unroll
        for (int k = 0; k < KITER; ++k) {
            int idx = k * NT + tid;                 // 0..1279
            int row = idx / W4;                     // 0..7
            int x0  = (idx - row * W4) * 4;         // 0..636
            float4 v = seg4[base + idx];
            sp_sum += softplus_fast(v.x) + softplus_fast(v.y)
                    + softplus_fast(v.z) + softplus_fast(v.w);
            unsigned w  = s_mask[row * NWORDS + (x0 >> 5)];
            unsigned mb = (w >> (x0 & 31)) & 0xFu;
            mx_sum += ((mb & 1u) ? v.x : 0.0f) + ((mb & 2u) ? v.y : 0.0f)
                    + ((mb & 4u) ? v.z : 0.0f) + ((mb & 8u) ? v.w : 0.0f);
        }
    }
    // non-eff image: contributes ln2/pixel, added analytically by the finisher.

    // --- deterministic block reduce ---
#pragma unroll
    for (int s = 32; s > 0; s >>= 1) {
        sp_sum += __shfl_xor(sp_sum, s, 64);
        mx_sum += __shfl_xor(mx_sum, s, 64);
    }
    const int wave = tid >> 6;
    if ((tid & 63) == 0) { s_r1[wave] = sp_sum; s_r2[wave] = mx_sum; }
    __syncthreads();
    if (tid == 0) {
        float a1 = 0.0f, a2 = 0.0f;
#pragma unroll
        for (int w = 0; w < NT / 64; ++w) { a1 += s_r1[w]; a2 += s_r2[w]; }
        partial[bid] = make_float2(a1, a2);
        __threadfence();                            // publish partial
        unsigned old = atomicAdd(counter, 1u);
        s_last = (old == GRID - 1) ? 1 : 0;
    }
    __syncthreads();
    if (!s_last) return;

    // ================= finisher: runs in the last block only =================
    __threadfence();                                // acquire all partials
    float a1 = 0.0f, a2 = 0.0f;
    for (int i = tid; i < GRID; i += NT) {          // fixed per-thread order
        float2 p = partial[i];
        a1 += p.x; a2 += p.y;
    }
#pragma unroll
    for (int s = 32; s > 0; s >>= 1) {
        a1 += __shfl_xor(a1, s, 64);
        a2 += __shfl_xor(a2, s, 64);
    }
    __syncthreads();                                // reuse s_r1/s_r2
    if ((tid & 63) == 0) { s_r1[wave] = a1; s_r2[wave] = a2; }
    if (tid < B_IMG) s_has[tid] = 0;
    __syncthreads();
    for (int m = tid; m < M; m += NT) {
        int bi = batch_idx[m];
        bi = min(max(bi, 0), B_IMG - 1);
        s_has[bi] = 1;                              // benign race
    }
    __syncthreads();
    if (tid == 0) {
        float t1 = 0.0f, t2 = 0.0f;
#pragma unroll
        for (int w = 0; w < NT / 64; ++w) { t1 += s_r1[w]; t2 += s_r2[w]; }
        int n_eff = 0;
        for (int bi = 0; bi < B_IMG; ++bi)
            n_eff += (is_seg[bi] == 0 && s_has[bi]) ? 1 : 0;
        float noneff_px = (float)(B_IMG - n_eff) * (float)H_DIM * (float)W_DIM;
        float total = t1 - t2 + LN2F * noneff_px;
        out[0] = (n_eff > 0) ? LOSS_WEIGHT * (total / NPIX) : 0.0f;
    }
}

// ---------------------------------------------------------------------------
extern "C" void kernel_launch(void* const* d_in, const int* in_sizes, int n_in,
                              void* d_out, int out_size, void* d_ws, size_t ws_size,
                              hipStream_t stream) {
    const float4*        seg4      = (const float4*)d_in[0];
    const float*         bboxes    = (const float*)d_in[1];
    const int*           batch_idx = (const int*)d_in[2];
    const unsigned char* is_seg    = (const unsigned char*)d_in[3];
    float*               out       = (float*)d_out;
    const int M = in_sizes[1] / 4;

    char* ws = (char*)d_ws;
    unsigned* counter = (unsigned*)ws;              // 4 B, zeroed below
    float2*   partial = (float2*)(ws + 16);         // GRID * 8 B

    hipMemsetAsync(counter, 0, sizeof(unsigned), stream);  // capture-safe memset node
    fused<<<GRID, NT, 0, stream>>>(seg4, bboxes, batch_idx, is_seg, M,
                                   partial, counter, out);
}

// Round 4
// 31.515 us; speedup vs baseline: 1.4514x; 1.4514x over previous
//
#include <hip/hip_runtime.h>
#include <hip/hip_bf16.h>
#include <math.h>

#define B_IMG 16
#define H_DIM 640
#define W_DIM 640
#define W4    160                       // float4 per row
#define RPB   8                         // rows per block
#define BLK_F4 (RPB * W4)               // 1280 float4 per block
#define BPI   (H_DIM / RPB)             // 80 blocks per image
#define GRID  (B_IMG * BPI)             // 1280 blocks, each owns 8 rows of ONE image
#define NT    256
#define KITER (BLK_F4 / NT)             // 5 float4 per thread
#define NWORDS (W_DIM / 32)             // 20 u32 per row bitmask
#define NPIX  ((float)B_IMG * H_DIM * W_DIM)
#define LOSS_WEIGHT 0.1f
#define LN2F 0.69314718055994530942f
#define MAXB 512

__device__ __forceinline__ float softplus_fast(float v) {
    return fmaxf(v, 0.0f) + __logf(1.0f + __expf(-fabsf(v)));
}

__global__ void __launch_bounds__(NT)
fused(const float4* __restrict__ seg4,
      const float*  __restrict__ bboxes,
      const int*    __restrict__ batch_idx,
      const unsigned char* __restrict__ is_seg,
      int M,
      float*    __restrict__ p1,        // [GRID] softplus partials
      float*    __restrict__ p2,        // [GRID] masked-v partials
      unsigned* __restrict__ counter,   // zeroed each call via memset node
      float*    __restrict__ out)
{
    __shared__ int      s_n;
    __shared__ int4     s_box[MAXB];                // this image's boxes (x1,y1,x2,y2)
    __shared__ unsigned s_mask[RPB * NWORDS];       // 8 rows x 640-bit
    __shared__ float    s_r1[NT / 64], s_r2[NT / 64];
    __shared__ int      s_last;
    __shared__ int      s_has[B_IMG];

    const int tid = threadIdx.x;
    const int bid = blockIdx.x;
    const int b   = bid / BPI;                      // image (uniform per block)
    const int y0  = (bid - b * BPI) * RPB;          // first row in image

    if (tid == 0) s_n = 0;
    __syncthreads();

    // --- gather this image's boxes (f32 math, clip [0,dim-1], trunc = ref) ---
    for (int m = tid; m < M; m += NT) {
        int bi = batch_idx[m];
        bi = min(max(bi, 0), B_IMG - 1);
        if (bi == b) {
            float cx = bboxes[4*m+0] * (float)W_DIM;
            float cy = bboxes[4*m+1] * (float)H_DIM;
            float bw = bboxes[4*m+2] * (float)W_DIM;
            float bh = bboxes[4*m+3] * (float)H_DIM;
            int x1 = (int)fminf(fmaxf(cx - bw*0.5f, 0.0f), (float)(W_DIM-1));
            int y1 = (int)fminf(fmaxf(cy - bh*0.5f, 0.0f), (float)(H_DIM-1));
            int x2 = (int)fminf(fmaxf(cx + bw*0.5f, 0.0f), (float)(W_DIM-1));
            int y2 = (int)fminf(fmaxf(cy + bh*0.5f, 0.0f), (float)(H_DIM-1));
            int p = atomicAdd(&s_n, 1);
            if (p < MAXB) s_box[p] = make_int4(x1, y1, x2, y2);
        }
    }
    __syncthreads();
    const int nb  = min(s_n, MAXB);
    const int eff = (is_seg[b] == 0 && nb > 0) ? 1 : 0;

    float sp_sum = 0.0f, mx_sum = 0.0f;

    if (eff) {
        // --- build per-row bitmasks: tid -> (row_local, word) ---
        if (tid < RPB * NWORDS) {
            int row  = tid / NWORDS;
            int word = tid - row * NWORDS;
            int y    = y0 + row;
            int wx0  = word * 32;
            unsigned acc = 0u;
            for (int i = 0; i < nb; ++i) {
                int4 bx = s_box[i];
                if (y >= bx.y && y <= bx.w) {
                    int lo = max(bx.x, wx0);
                    int hi = min(bx.z, wx0 + 31);
                    if (lo <= hi) {
                        unsigned span = (unsigned)(hi - lo + 1);
                        unsigned mset = (span >= 32u) ? 0xFFFFFFFFu
                                                      : ((1u << span) - 1u);
                        acc |= mset << (lo - wx0);
                    }
                }
            }
            s_mask[tid] = acc;
        }
        __syncthreads();

        // --- stream 5 float4 per thread, contiguous chunk, mask via bit test ---
        const size_t base = (size_t)bid * BLK_F4;
#pragma unroll
        for (int k = 0; k < KITER; ++k) {
            int idx = k * NT + tid;                 // 0..1279
            int row = idx / W4;                     // 0..7
            int x0  = (idx - row * W4) * 4;         // 0..636
            float4 v = seg4[base + idx];
            sp_sum += softplus_fast(v.x) + softplus_fast(v.y)
                    + softplus_fast(v.z) + softplus_fast(v.w);
            unsigned w  = s_mask[row * NWORDS + (x0 >> 5)];
            unsigned mb = (w >> (x0 & 31)) & 0xFu;
            mx_sum += ((mb & 1u) ? v.x : 0.0f) + ((mb & 2u) ? v.y : 0.0f)
                    + ((mb & 4u) ? v.z : 0.0f) + ((mb & 8u) ? v.w : 0.0f);
        }
    }
    // non-eff image: contributes ln2/pixel, added analytically by the finisher.

    // --- deterministic block reduce ---
#pragma unroll
    for (int s = 32; s > 0; s >>= 1) {
        sp_sum += __shfl_xor(sp_sum, s, 64);
        mx_sum += __shfl_xor(mx_sum, s, 64);
    }
    const int wave = tid >> 6;
    if ((tid & 63) == 0) { s_r1[wave] = sp_sum; s_r2[wave] = mx_sum; }
    __syncthreads();
    if (tid == 0) {
        float a1 = 0.0f, a2 = 0.0f;
#pragma unroll
        for (int w = 0; w < NT / 64; ++w) { a1 += s_r1[w]; a2 += s_r2[w]; }
        // Publish via agent-scope atomic RMWs (coherent at device coherence
        // point, no L2 writeback fence needed); order with explicit vmcnt(0)
        // so both stores have committed before the counter bump is visible.
        __hip_atomic_exchange(&p1[bid], a1, __ATOMIC_RELAXED, __HIP_MEMORY_SCOPE_AGENT);
        __hip_atomic_exchange(&p2[bid], a2, __ATOMIC_RELAXED, __HIP_MEMORY_SCOPE_AGENT);
        asm volatile("s_waitcnt vmcnt(0)" ::: "memory");
        unsigned old = __hip_atomic_fetch_add(counter, 1u,
                                              __ATOMIC_RELAXED, __HIP_MEMORY_SCOPE_AGENT);
        s_last = (old == (unsigned)(GRID - 1)) ? 1 : 0;
    }
    __syncthreads();
    if (!s_last) return;

    // ================= finisher: runs in the last block only =================
    float a1 = 0.0f, a2 = 0.0f;
    for (int i = tid; i < GRID; i += NT) {          // fixed per-thread order
        // RMW-loads: guaranteed coherent at agent scope; +0.0f is exact.
        a1 += __hip_atomic_fetch_add(&p1[i], 0.0f, __ATOMIC_RELAXED, __HIP_MEMORY_SCOPE_AGENT);
        a2 += __hip_atomic_fetch_add(&p2[i], 0.0f, __ATOMIC_RELAXED, __HIP_MEMORY_SCOPE_AGENT);
    }
#pragma unroll
    for (int s = 32; s > 0; s >>= 1) {
        a1 += __shfl_xor(a1, s, 64);
        a2 += __shfl_xor(a2, s, 64);
    }
    __syncthreads();                                // reuse s_r1/s_r2/s_has
    if ((tid & 63) == 0) { s_r1[wave] = a1; s_r2[wave] = a2; }
    if (tid < B_IMG) s_has[tid] = 0;
    __syncthreads();
    for (int m = tid; m < M; m += NT) {
        int bi = batch_idx[m];
        bi = min(max(bi, 0), B_IMG - 1);
        s_has[bi] = 1;                              // benign race
    }
    __syncthreads();
    if (tid == 0) {
        float t1 = 0.0f, t2 = 0.0f;
#pragma unroll
        for (int w = 0; w < NT / 64; ++w) { t1 += s_r1[w]; t2 += s_r2[w]; }
        int n_eff = 0;
        for (int bi = 0; bi < B_IMG; ++bi)
            n_eff += (is_seg[bi] == 0 && s_has[bi]) ? 1 : 0;
        float noneff_px = (float)(B_IMG - n_eff) * (float)H_DIM * (float)W_DIM;
        float total = t1 - t2 + LN2F * noneff_px;
        out[0] = (n_eff > 0) ? LOSS_WEIGHT * (total / NPIX) : 0.0f;
    }
}

// ---------------------------------------------------------------------------
extern "C" void kernel_launch(void* const* d_in, const int* in_sizes, int n_in,
                              void* d_out, int out_size, void* d_ws, size_t ws_size,
                              hipStream_t stream) {
    const float4*        seg4      = (const float4*)d_in[0];
    const float*         bboxes    = (const float*)d_in[1];
    const int*           batch_idx = (const int*)d_in[2];
    const unsigned char* is_seg    = (const unsigned char*)d_in[3];
    float*               out       = (float*)d_out;
    const int M = in_sizes[1] / 4;

    char* ws = (char*)d_ws;
    unsigned* counter = (unsigned*)ws;              // 4 B, zeroed below
    float*    p1      = (float*)(ws + 16);          // GRID * 4 B
    float*    p2      = (float*)(ws + 16 + GRID * sizeof(float));

    hipMemsetAsync(counter, 0, sizeof(unsigned), stream);  // capture-safe node
    fused<<<GRID, NT, 0, stream>>>(seg4, bboxes, batch_idx, is_seg, M,
                                   p1, p2, counter, out);
}

// Round 5
// 16.355 us; speedup vs baseline: 2.7969x; 1.9269x over previous
//
#include <hip/hip_runtime.h>
#include <hip/hip_bf16.h>
#include <math.h>

#define B_IMG 16
#define H_DIM 640
#define W_DIM 640
#define W4    160                       // float4 per row
#define RPB   8                         // rows per block
#define BLK_F4 (RPB * W4)               // 1280 float4 per block
#define BPI   (H_DIM / RPB)             // 80 blocks per image
#define GRID  (B_IMG * BPI)             // 1280 blocks, each owns 8 rows of ONE image
#define NT    256
#define KITER (BLK_F4 / NT)             // 5 float4 per thread
#define NWORDS (W_DIM / 32)             // 20 u32 per row bitmask
#define NPIX  ((float)B_IMG * H_DIM * W_DIM)
#define LOSS_WEIGHT 0.1f
#define LN2F 0.69314718055994530942f
#define MAXB 512

__device__ __forceinline__ float softplus_fast(float v) {
    return fmaxf(v, 0.0f) + __logf(1.0f + __expf(-fabsf(v)));
}

// ---------------------------------------------------------------------------
// Kernel 1: each block owns an 8-row slab of one image. Rasterize that
// image's boxes into a per-row 640-bit LDS mask, then stream the slab as
// float4 (1 LDS word + shift/and per 4 px). Plain store of the partial;
// the kernel boundary provides cross-block visibility.
// ---------------------------------------------------------------------------
__global__ void __launch_bounds__(NT)
slab_reduce(const float4* __restrict__ seg4,
            const float*  __restrict__ bboxes,
            const int*    __restrict__ batch_idx,
            const unsigned char* __restrict__ is_seg,
            int M,
            float2* __restrict__ partial)       // [GRID]
{
    __shared__ int      s_n;
    __shared__ int4     s_box[MAXB];            // this image's boxes (x1,y1,x2,y2)
    __shared__ unsigned s_mask[RPB * NWORDS];   // 8 rows x 640-bit
    __shared__ float    s_r1[NT / 64], s_r2[NT / 64];

    const int tid = threadIdx.x;
    const int bid = blockIdx.x;
    const int b   = bid / BPI;                  // image (uniform per block)
    const int y0  = (bid - b * BPI) * RPB;      // first row of slab

    if (tid == 0) s_n = 0;
    __syncthreads();

    // --- gather this image's boxes (f32 math, clip [0,dim-1], trunc = ref) ---
    for (int m = tid; m < M; m += NT) {
        int bi = batch_idx[m];
        bi = min(max(bi, 0), B_IMG - 1);
        if (bi == b) {
            float cx = bboxes[4*m+0] * (float)W_DIM;
            float cy = bboxes[4*m+1] * (float)H_DIM;
            float bw = bboxes[4*m+2] * (float)W_DIM;
            float bh = bboxes[4*m+3] * (float)H_DIM;
            int x1 = (int)fminf(fmaxf(cx - bw*0.5f, 0.0f), (float)(W_DIM-1));
            int y1 = (int)fminf(fmaxf(cy - bh*0.5f, 0.0f), (float)(H_DIM-1));
            int x2 = (int)fminf(fmaxf(cx + bw*0.5f, 0.0f), (float)(W_DIM-1));
            int y2 = (int)fminf(fmaxf(cy + bh*0.5f, 0.0f), (float)(H_DIM-1));
            int p = atomicAdd(&s_n, 1);
            if (p < MAXB) s_box[p] = make_int4(x1, y1, x2, y2);
        }
    }
    __syncthreads();
    const int nb  = min(s_n, MAXB);
    const int eff = (is_seg[b] == 0 && nb > 0) ? 1 : 0;

    float sp_sum = 0.0f, mx_sum = 0.0f;

    if (eff) {
        // --- build per-row bitmasks: tid -> (row_local, word) ---
        if (tid < RPB * NWORDS) {
            int row  = tid / NWORDS;
            int word = tid - row * NWORDS;
            int y    = y0 + row;
            int wx0  = word * 32;
            unsigned acc = 0u;
            for (int i = 0; i < nb; ++i) {
                int4 bx = s_box[i];                     // broadcast read
                if (y >= bx.y && y <= bx.w) {
                    int lo = max(bx.x, wx0);
                    int hi = min(bx.z, wx0 + 31);
                    if (lo <= hi) {
                        unsigned span = (unsigned)(hi - lo + 1);
                        unsigned mset = (span >= 32u) ? 0xFFFFFFFFu
                                                      : ((1u << span) - 1u);
                        acc |= mset << (lo - wx0);
                    }
                }
            }
            s_mask[tid] = acc;
        }
        __syncthreads();

        // --- stream 5 float4/thread, contiguous slab, mask via LDS bit test ---
        const size_t base = (size_t)bid * BLK_F4;
#pragma unroll
        for (int k = 0; k < KITER; ++k) {
            int idx = k * NT + tid;                     // 0..1279
            int row = idx / W4;                         // 0..7
            int x0  = (idx - row * W4) * 4;             // 0..636
            float4 v = seg4[base + idx];
            sp_sum += softplus_fast(v.x) + softplus_fast(v.y)
                    + softplus_fast(v.z) + softplus_fast(v.w);
            unsigned w  = s_mask[row * NWORDS + (x0 >> 5)];
            unsigned mb = (w >> (x0 & 31)) & 0xFu;
            mx_sum += ((mb & 1u) ? v.x : 0.0f) + ((mb & 2u) ? v.y : 0.0f)
                    + ((mb & 4u) ? v.z : 0.0f) + ((mb & 8u) ? v.w : 0.0f);
        }
    }
    // non-eff image: contributes ln2/pixel, handled analytically in kernel 2.

    // --- deterministic block reduce: wave butterfly + LDS across waves ---
#pragma unroll
    for (int s = 32; s > 0; s >>= 1) {
        sp_sum += __shfl_xor(sp_sum, s, 64);
        mx_sum += __shfl_xor(mx_sum, s, 64);
    }
    const int wave = tid >> 6;
    if ((tid & 63) == 0) { s_r1[wave] = sp_sum; s_r2[wave] = mx_sum; }
    __syncthreads();
    if (tid == 0) {
        float a1 = 0.0f, a2 = 0.0f;
#pragma unroll
        for (int w = 0; w < NT / 64; ++w) { a1 += s_r1[w]; a2 += s_r2[w]; }
        partial[bid] = make_float2(a1, a2);             // plain store
    }
}

// ---------------------------------------------------------------------------
// Kernel 2: deterministic final reduction + eff bookkeeping + loss assembly.
// ---------------------------------------------------------------------------
__global__ void __launch_bounds__(NT)
final_reduce(const float2* __restrict__ partial,
             const int*    __restrict__ batch_idx,
             const unsigned char* __restrict__ is_seg,
             int M,
             float* __restrict__ out)
{
    __shared__ int   s_has[B_IMG];
    __shared__ float s1[NT / 64];
    __shared__ float s2[NT / 64];
    const int tid = threadIdx.x;
    if (tid < B_IMG) s_has[tid] = 0;
    __syncthreads();
    for (int m = tid; m < M; m += NT) {
        int b = batch_idx[m];
        b = min(max(b, 0), B_IMG - 1);
        s_has[b] = 1;                                   // benign race
    }
    __syncthreads();

    float a1 = 0.0f, a2 = 0.0f;
    for (int i = tid; i < GRID; i += NT) {              // fixed per-thread order
        float2 p = partial[i];
        a1 += p.x; a2 += p.y;
    }
#pragma unroll
    for (int s = 32; s > 0; s >>= 1) {
        a1 += __shfl_xor(a1, s, 64);
        a2 += __shfl_xor(a2, s, 64);
    }
    const int wave = tid >> 6;
    if ((tid & 63) == 0) { s1[wave] = a1; s2[wave] = a2; }
    __syncthreads();
    if (tid == 0) {
        float t1 = 0.0f, t2 = 0.0f;
#pragma unroll
        for (int w = 0; w < NT / 64; ++w) { t1 += s1[w]; t2 += s2[w]; }
        int n_eff = 0;
        for (int b = 0; b < B_IMG; ++b)
            n_eff += (is_seg[b] == 0 && s_has[b]) ? 1 : 0;
        float noneff_px = (float)(B_IMG - n_eff) * (float)H_DIM * (float)W_DIM;
        float total = t1 - t2 + LN2F * noneff_px;
        out[0] = (n_eff > 0) ? LOSS_WEIGHT * (total / NPIX) : 0.0f;
    }
}

// ---------------------------------------------------------------------------
extern "C" void kernel_launch(void* const* d_in, const int* in_sizes, int n_in,
                              void* d_out, int out_size, void* d_ws, size_t ws_size,
                              hipStream_t stream) {
    const float4*        seg4      = (const float4*)d_in[0];
    const float*         bboxes    = (const float*)d_in[1];
    const int*           batch_idx = (const int*)d_in[2];
    const unsigned char* is_seg    = (const unsigned char*)d_in[3];
    float*               out       = (float*)d_out;
    const int M = in_sizes[1] / 4;

    float2* partial = (float2*)d_ws;                    // GRID * 8 B

    slab_reduce<<<GRID, NT, 0, stream>>>(seg4, bboxes, batch_idx, is_seg, M, partial);
    final_reduce<<<1, NT, 0, stream>>>(partial, batch_idx, is_seg, M, out);
}

// Round 6
// 16.031 us; speedup vs baseline: 2.8534x; 1.0202x over previous
//
#include <hip/hip_runtime.h>
#include <hip/hip_bf16.h>
#include <math.h>

#define B_IMG 16
#define H_DIM 640
#define W_DIM 640
#define W4    160                       // float4 per row
#define RPB   8                         // rows per block
#define BLK_F4 (RPB * W4)               // 1280 float4 per block
#define BPI   (H_DIM / RPB)             // 80 blocks per image
#define GRID  (B_IMG * BPI)             // 1280 blocks, each owns 8 rows of ONE image
#define NT    256
#define KITER (BLK_F4 / NT)             // 5 float4 per thread
#define NWORDS (W_DIM / 32)             // 20 u32 per row bitmask
#define NPIX  ((float)B_IMG * H_DIM * W_DIM)
#define LOSS_WEIGHT 0.1f
#define LN2F 0.69314718055994530942f
#define MAXB 512

__device__ __forceinline__ float softplus_fast(float v) {
    return fmaxf(v, 0.0f) + __logf(1.0f + __expf(-fabsf(v)));
}

// ---------------------------------------------------------------------------
// Kernel 1: each block owns an 8-row slab of one image.
// T14 split: issue the slab's 5 float4 loads FIRST (addresses independent of
// LDS), hide their latency under box-gather + bitmask build, consume after.
// ---------------------------------------------------------------------------
__global__ void __launch_bounds__(NT)
slab_reduce(const float4* __restrict__ seg4,
            const float*  __restrict__ bboxes,
            const int*    __restrict__ batch_idx,
            const unsigned char* __restrict__ is_seg,
            int M,
            float2* __restrict__ partial)       // [GRID]
{
    __shared__ int      s_n;
    __shared__ int4     s_box[MAXB];            // this image's boxes (x1,y1,x2,y2)
    __shared__ unsigned s_mask[RPB * NWORDS];   // 8 rows x 640-bit
    __shared__ float    s_r1[NT / 64], s_r2[NT / 64];

    const int tid = threadIdx.x;
    const int bid = blockIdx.x;
    const int b   = bid / BPI;                  // image (uniform per block)
    const int y0  = (bid - b * BPI) * RPB;      // first row of slab

    // --- prefetch: issue all 5 slab loads before any LDS/setup work ---
    const size_t base = (size_t)bid * BLK_F4;
    float4 v0 = seg4[base + 0 * NT + tid];
    float4 v1 = seg4[base + 1 * NT + tid];
    float4 v2 = seg4[base + 2 * NT + tid];
    float4 v3 = seg4[base + 3 * NT + tid];
    float4 v4 = seg4[base + 4 * NT + tid];

    if (tid == 0) s_n = 0;
    __syncthreads();

    // --- gather this image's boxes (f32 math, clip [0,dim-1], trunc = ref) ---
    for (int m = tid; m < M; m += NT) {
        int bi = batch_idx[m];
        bi = min(max(bi, 0), B_IMG - 1);
        if (bi == b) {
            float cx = bboxes[4*m+0] * (float)W_DIM;
            float cy = bboxes[4*m+1] * (float)H_DIM;
            float bw = bboxes[4*m+2] * (float)W_DIM;
            float bh = bboxes[4*m+3] * (float)H_DIM;
            int x1 = (int)fminf(fmaxf(cx - bw*0.5f, 0.0f), (float)(W_DIM-1));
            int y1 = (int)fminf(fmaxf(cy - bh*0.5f, 0.0f), (float)(H_DIM-1));
            int x2 = (int)fminf(fmaxf(cx + bw*0.5f, 0.0f), (float)(W_DIM-1));
            int y2 = (int)fminf(fmaxf(cy + bh*0.5f, 0.0f), (float)(H_DIM-1));
            int p = atomicAdd(&s_n, 1);
            if (p < MAXB) s_box[p] = make_int4(x1, y1, x2, y2);
        }
    }
    __syncthreads();
    const int nb  = min(s_n, MAXB);
    const int eff = (is_seg[b] == 0 && nb > 0) ? 1 : 0;

    float sp_sum = 0.0f, mx_sum = 0.0f;

    if (eff) {
        // --- build per-row bitmasks: tid -> (row_local, word) ---
        if (tid < RPB * NWORDS) {
            int row  = tid / NWORDS;
            int word = tid - row * NWORDS;
            int y    = y0 + row;
            int wx0  = word * 32;
            unsigned acc = 0u;
            for (int i = 0; i < nb; ++i) {
                int4 bx = s_box[i];                     // broadcast read
                if (y >= bx.y && y <= bx.w) {
                    int lo = max(bx.x, wx0);
                    int hi = min(bx.z, wx0 + 31);
                    if (lo <= hi) {
                        unsigned span = (unsigned)(hi - lo + 1);
                        unsigned mset = (span >= 32u) ? 0xFFFFFFFFu
                                                      : ((1u << span) - 1u);
                        acc |= mset << (lo - wx0);
                    }
                }
            }
            s_mask[tid] = acc;
        }
        __syncthreads();

        // --- consume prefetched registers; mask via LDS bit test ---
        float4 vv[KITER] = {v0, v1, v2, v3, v4};
#pragma unroll
        for (int k = 0; k < KITER; ++k) {
            int idx = k * NT + tid;                     // 0..1279
            int row = idx / W4;                         // 0..7
            int x0  = (idx - row * W4) * 4;             // 0..636
            float4 v = vv[k];
            sp_sum += softplus_fast(v.x) + softplus_fast(v.y)
                    + softplus_fast(v.z) + softplus_fast(v.w);
            unsigned w  = s_mask[row * NWORDS + (x0 >> 5)];
            unsigned mb = (w >> (x0 & 31)) & 0xFu;
            mx_sum += ((mb & 1u) ? v.x : 0.0f) + ((mb & 2u) ? v.y : 0.0f)
                    + ((mb & 4u) ? v.z : 0.0f) + ((mb & 8u) ? v.w : 0.0f);
        }
    }
    // non-eff image: contributes ln2/pixel, handled analytically in kernel 2.

    // --- deterministic block reduce: wave butterfly + LDS across waves ---
#pragma unroll
    for (int s = 32; s > 0; s >>= 1) {
        sp_sum += __shfl_xor(sp_sum, s, 64);
        mx_sum += __shfl_xor(mx_sum, s, 64);
    }
    const int wave = tid >> 6;
    if ((tid & 63) == 0) { s_r1[wave] = sp_sum; s_r2[wave] = mx_sum; }
    __syncthreads();
    if (tid == 0) {
        float a1 = 0.0f, a2 = 0.0f;
#pragma unroll
        for (int w = 0; w < NT / 64; ++w) { a1 += s_r1[w]; a2 += s_r2[w]; }
        partial[bid] = make_float2(a1, a2);             // plain store
    }
}

// ---------------------------------------------------------------------------
// Kernel 2: deterministic final reduction + eff bookkeeping + loss assembly.
// ---------------------------------------------------------------------------
__global__ void __launch_bounds__(NT)
final_reduce(const float2* __restrict__ partial,
             const int*    __restrict__ batch_idx,
             const unsigned char* __restrict__ is_seg,
             int M,
             float* __restrict__ out)
{
    __shared__ int   s_has[B_IMG];
    __shared__ float s1[NT / 64];
    __shared__ float s2[NT / 64];
    const int tid = threadIdx.x;

    // prefetch partials first (T14 again), overlap with s_has setup
    float a1 = 0.0f, a2 = 0.0f;
    float2 pv[GRID / NT];
#pragma unroll
    for (int k = 0; k < GRID / NT; ++k) pv[k] = partial[k * NT + tid];

    if (tid < B_IMG) s_has[tid] = 0;
    __syncthreads();
    for (int m = tid; m < M; m += NT) {
        int b = batch_idx[m];
        b = min(max(b, 0), B_IMG - 1);
        s_has[b] = 1;                                   // benign race
    }
    __syncthreads();

#pragma unroll
    for (int k = 0; k < GRID / NT; ++k) { a1 += pv[k].x; a2 += pv[k].y; }
#pragma unroll
    for (int s = 32; s > 0; s >>= 1) {
        a1 += __shfl_xor(a1, s, 64);
        a2 += __shfl_xor(a2, s, 64);
    }
    const int wave = tid >> 6;
    if ((tid & 63) == 0) { s1[wave] = a1; s2[wave] = a2; }
    __syncthreads();
    if (tid == 0) {
        float t1 = 0.0f, t2 = 0.0f;
#pragma unroll
        for (int w = 0; w < NT / 64; ++w) { t1 += s1[w]; t2 += s2[w]; }
        int n_eff = 0;
        for (int b = 0; b < B_IMG; ++b)
            n_eff += (is_seg[b] == 0 && s_has[b]) ? 1 : 0;
        float noneff_px = (float)(B_IMG - n_eff) * (float)H_DIM * (float)W_DIM;
        float total = t1 - t2 + LN2F * noneff_px;
        out[0] = (n_eff > 0) ? LOSS_WEIGHT * (total / NPIX) : 0.0f;
    }
}

// ---------------------------------------------------------------------------
extern "C" void kernel_launch(void* const* d_in, const int* in_sizes, int n_in,
                              void* d_out, int out_size, void* d_ws, size_t ws_size,
                              hipStream_t stream) {
    const float4*        seg4      = (const float4*)d_in[0];
    const float*         bboxes    = (const float*)d_in[1];
    const int*           batch_idx = (const int*)d_in[2];
    const unsigned char* is_seg    = (const unsigned char*)d_in[3];
    float*               out       = (float*)d_out;
    const int M = in_sizes[1] / 4;

    float2* partial = (float2*)d_ws;                    // GRID * 8 B

    slab_reduce<<<GRID, NT, 0, stream>>>(seg4, bboxes, batch_idx, is_seg, M, partial);
    final_reduce<<<1, NT, 0, stream>>>(partial, batch_idx, is_seg, M, out);
}